// Round 9
// baseline (530.875 us; speedup 1.0000x reference)
//
#include <hip/hip_runtime.h>

#define NH 12
#define HD 32
#define DIMC 384
#define BATCH 32
#define HWIMG 56
#define NWIN 2048          // 32 batches * 64 windows
#define NROWS 100352       // 2048*49 == 32*3136
#define QKV_M 1152
#define KDIM 384
#define QSCALE 0.17677669529663687f

typedef __attribute__((ext_vector_type(8))) short short8;
typedef __attribute__((ext_vector_type(4))) short short4v;
typedef __attribute__((ext_vector_type(4))) float f32x4;

typedef const __attribute__((address_space(1))) unsigned int* gas_ptr;
typedef __attribute__((address_space(3))) unsigned int* las_ptr;

__device__ __forceinline__ unsigned short f2bf(float f) {
    union { float f; unsigned u; } v; v.f = f;
    unsigned r = v.u + 0x7FFF + ((v.u >> 16) & 1);
    return (unsigned short)(r >> 16);
}

// ---------------- fp32 -> bf16 weight convert ----------------
__global__ __launch_bounds__(256) void cvt_w(const float* __restrict__ in,
                                             unsigned short* __restrict__ out, int n) {
    int i = blockIdx.x * 256 + threadIdx.x;
    if (i < n) out[i] = f2bf(in[i]);
}

// ---------------- x [B,384,56,56] fp32 -> xt [NROWS,384] bf16 (window-gathered) -------
__global__ __launch_bounds__(256) void cvt_x(const float* __restrict__ x,
                                             unsigned short* __restrict__ xt) {
    __shared__ float tile[32][33];
    const int b = blockIdx.z, c0 = blockIdx.y * 32, n0 = blockIdx.x * 32;
    const int tid = threadIdx.x;
    const int cl = tid >> 5, nl = tid & 31;
    #pragma unroll
    for (int p = 0; p < 4; ++p)
        tile[cl + p * 8][nl] = x[((size_t)b * DIMC + c0 + cl + p * 8) * 3136 + n0 + nl];
    __syncthreads();
    const int nl2 = tid >> 3, cq = (tid & 7) * 4;
    const int n = n0 + nl2;
    const int nh = n / HWIMG, nw = n % HWIMG;
    const int row = ((b * 64 + (nh / 7) * 8 + nw / 7) * 49 + (nh % 7) * 7 + nw % 7);
    short4v pk;
    #pragma unroll
    for (int u = 0; u < 4; ++u) pk[u] = (short)f2bf(tile[cq + u][nl2]);
    *(short4v*)(xt + (size_t)row * KDIM + c0 + cq) = pk;
}

// ---------------- bias expand: biasp[h][j:64][i:64] fp32, transposed & padded ----------
__global__ __launch_bounds__(256) void fill_bias(const float* __restrict__ bias_table,
                                                 const int* __restrict__ rel_index,
                                                 float* __restrict__ biasp) {
    int id = blockIdx.x * 256 + threadIdx.x;   // 12*4096
    int h = id >> 12, r = id & 4095;
    int j = r >> 6, i = r & 63;
    float v = 0.f;
    if (i < 49 && j < 49) v = bias_table[rel_index[i * 49 + j] * NH + h];
    biasp[id] = v;
}

// ============ FUSED per-window QKV-GEMM + attention ============
// Block = 1 window, 4 waves; wave wv handles heads {wv, wv+4, wv+8}.
// x window rows in LDS (swizzled); w_qkv B-frags streamed from L2.
// q/k bounced through per-wave padded LDS to convert C-layout -> frag layout;
// V aliases the K bounce region (lgkmcnt fences guard the alias).
__global__ __launch_bounds__(256, 2) void fused_qkv_attn(
    const unsigned short* __restrict__ xt,    // [NROWS][384] window-gathered
    const unsigned short* __restrict__ wqb,   // [1152][384] bf16
    const float* __restrict__ biasp,          // [12][64][64]
    unsigned short* __restrict__ att)         // [B*3136][384] spatial-major
{
    __shared__ char xl[49 * 768];            // 37632B, XOR-swizzled 16B slots
    __shared__ short bq[4][64 * 40];         // per-wave Q bounce [row][40]
    __shared__ short bk[4][64 * 40];         // per-wave K bounce; V aliases as [32][72]
    const int tid = threadIdx.x;
    const int lane = tid & 63;
    const int wv = tid >> 6;
    const int g = lane >> 4, c = lane & 15;
    const int win = blockIdx.x;

    // ---- stage x window (49 rows x 768B), inverse-swizzled source, linear dest ----
    const char* xbase = (const char*)(xt + (size_t)win * 49 * KDIM);
    #pragma unroll
    for (int it = 0; it < 10; ++it) {
        int chunk = it * 256 + tid;
        if (chunk < 2352) {
            int row = chunk / 48, cs = chunk % 48;
            int scol = (cs >> 3) * 128 + (((cs & 7) ^ (row & 7)) * 16);
            __builtin_amdgcn_global_load_lds(
                (gas_ptr)(xbase + (size_t)row * 768 + scol),
                (las_ptr)(xl + chunk * 16), 16, 0, 0);
        }
    }
    __syncthreads();

    short* Q = bq[wv];
    short* K = bk[wv];
    short* V = bk[wv];   // alias, used as [32 d][72 stride]

    int rcl[4];
    #pragma unroll
    for (int i = 0; i < 4; ++i) { int r = i * 16 + c; rcl[i] = (r > 48) ? 48 : r; }

    const int wl = win & 63, bb = win >> 6;
    const size_t obase = (size_t)bb * 3136 * DIMC;
    const int nsp0 = (wl >> 3) * 7 * HWIMG + (wl & 7) * 7;

    for (int hi = 0; hi < 3; ++hi) {
        const int head = wv + hi * 4;
        const char* wb = (const char*)wqb + (size_t)head * 32 * 768;

        // ---- QKV GEMM: out 64 rows x (q32|k32|v32), K=384 ----
        f32x4 aq[4][2] = {}, ak[4][2] = {}, av[4][2] = {};
        #pragma unroll
        for (int kt = 0; kt < 12; ++kt) {
            short8 af[4];
            #pragma unroll
            for (int i = 0; i < 4; ++i) {
                int slot = ((kt & 1) * 4 + g) ^ (rcl[i] & 7);
                af[i] = *(const short8*)(xl + rcl[i] * 768 + (kt >> 1) * 128 + slot * 16);
            }
            #pragma unroll
            for (int p = 0; p < 3; ++p) {
                #pragma unroll
                for (int tn = 0; tn < 2; ++tn) {
                    short8 bf = *(const short8*)(wb + (size_t)(p * 384 + tn * 16 + c) * 768
                                                 + kt * 64 + g * 16);
                    #pragma unroll
                    for (int i = 0; i < 4; ++i) {
                        if (p == 0) aq[i][tn] = __builtin_amdgcn_mfma_f32_16x16x32_bf16(af[i], bf, aq[i][tn], 0, 0, 0);
                        else if (p == 1) ak[i][tn] = __builtin_amdgcn_mfma_f32_16x16x32_bf16(af[i], bf, ak[i][tn], 0, 0, 0);
                        else av[i][tn] = __builtin_amdgcn_mfma_f32_16x16x32_bf16(af[i], bf, av[i][tn], 0, 0, 0);
                    }
                }
            }
        }

        // ---- bounce q,k: C-layout (row = i*16+g*4+e, col = tn*16+c) -> [row][40] ----
        #pragma unroll
        for (int i = 0; i < 4; ++i)
            #pragma unroll
            for (int tn = 0; tn < 2; ++tn)
                #pragma unroll
                for (int e = 0; e < 4; ++e) {
                    int row = i * 16 + g * 4 + e, col = tn * 16 + c;
                    Q[row * 40 + col] = (short)f2bf(aq[i][tn][e] * QSCALE);
                    K[row * 40 + col] = (short)f2bf(ak[i][tn][e]);
                }
        asm volatile("s_waitcnt lgkmcnt(0)" ::: "memory");

        short8 qf[4], kf[4];
        #pragma unroll
        for (int a = 0; a < 4; ++a) {
            int r = a * 16 + c;
            qf[a] = *(const short8*)(Q + r * 40 + g * 8);
            kf[a] = *(const short8*)(K + r * 40 + g * 8);
        }
        asm volatile("s_waitcnt lgkmcnt(0)" ::: "memory");  // kf/qf in regs; K region now free

        // ---- write V into K-alias region as [d][j], stride 72 ----
        #pragma unroll
        for (int i = 0; i < 4; ++i)
            #pragma unroll
            for (int tn = 0; tn < 2; ++tn)
                #pragma unroll
                for (int e = 0; e < 4; ++e)
                    V[(tn * 16 + c) * 72 + i * 16 + g * 4 + e] = (short)f2bf(av[i][tn][e]);

        // ---- QK^T: S^T fragments (rows j = a*16+g*4+e, cols i = bi*16+c) ----
        f32x4 s[4][4] = {};
        #pragma unroll
        for (int a = 0; a < 4; ++a)
            #pragma unroll
            for (int bi = 0; bi < 4; ++bi)
                s[a][bi] = __builtin_amdgcn_mfma_f32_16x16x32_bf16(kf[a], qf[bi], s[a][bi], 0, 0, 0);

        // ---- softmax (per-column; j-reduce = 16 in-lane + shfl 16,32) ----
        const float* bp = biasp + head * 4096;
        #pragma unroll
        for (int bi = 0; bi < 4; ++bi) {
            float mx = -1e30f;
            #pragma unroll
            for (int a = 0; a < 4; ++a) {
                #pragma unroll
                for (int e = 0; e < 4; ++e) {
                    int j = a * 16 + g * 4 + e;
                    float sv = s[a][bi][e] + bp[j * 64 + bi * 16 + c];
                    sv = (j < 49) ? sv : -1e30f;
                    s[a][bi][e] = sv;
                    mx = fmaxf(mx, sv);
                }
            }
            mx = fmaxf(mx, __shfl_xor(mx, 16));
            mx = fmaxf(mx, __shfl_xor(mx, 32));
            float sum = 0.f;
            #pragma unroll
            for (int a = 0; a < 4; ++a) {
                #pragma unroll
                for (int e = 0; e < 4; ++e) {
                    int j = a * 16 + g * 4 + e;
                    float pv = (j < 49) ? __expf(s[a][bi][e] - mx) : 0.f;
                    s[a][bi][e] = pv;
                    sum += pv;
                }
            }
            sum += __shfl_xor(sum, 16);
            sum += __shfl_xor(sum, 32);
            float inv = 1.0f / sum;
            #pragma unroll
            for (int a = 0; a < 4; ++a)
                #pragma unroll
                for (int e = 0; e < 4; ++e)
                    s[a][bi][e] *= inv;
        }

        // ---- pack P pairs along j ----
        unsigned pk[4][4][2];
        #pragma unroll
        for (int a = 0; a < 4; ++a)
            #pragma unroll
            for (int bi = 0; bi < 4; ++bi)
                #pragma unroll
                for (int h = 0; h < 2; ++h)
                    pk[a][bi][h] = (unsigned)f2bf(s[a][bi][2 * h]) |
                                   ((unsigned)f2bf(s[a][bi][2 * h + 1]) << 16);

        // ---- V fragments from LDS ----
        asm volatile("s_waitcnt lgkmcnt(0)" ::: "memory");
        short8 vf[2][2];
        #pragma unroll
        for (int tn = 0; tn < 2; ++tn)
            #pragma unroll
            for (int ks = 0; ks < 2; ++ks)
                vf[tn][ks] = *(const short8*)(V + (tn * 16 + c) * 72 + ks * 32 + g * 8);

        // ---- PV: A = P^T via ds_bpermute repack ----
        f32x4 o[4][2] = {};
        const int gsel = g >> 1;
        const int sgb = 2 * (g & 1);
        #pragma unroll
        for (int ks = 0; ks < 2; ++ks) {
            #pragma unroll
            for (int to = 0; to < 4; ++to) {
                union { int w[4]; short8 v; } u;
                #pragma unroll
                for (int w = 0; w < 4; ++w) {
                    int srcl = ((sgb + (w >> 1)) * 16 + c) << 2;
                    int rA = __builtin_amdgcn_ds_bpermute(srcl, (int)pk[ks * 2 + 0][to][w & 1]);
                    int rB = __builtin_amdgcn_ds_bpermute(srcl, (int)pk[ks * 2 + 1][to][w & 1]);
                    u.w[w] = gsel ? rB : rA;
                }
                #pragma unroll
                for (int tn = 0; tn < 2; ++tn)
                    o[to][tn] = __builtin_amdgcn_mfma_f32_16x16x32_bf16(u.v, vf[tn][ks], o[to][tn], 0, 0, 0);
            }
        }

        // ---- store O rows (i<49) to spatial-major att ----
        #pragma unroll
        for (int to = 0; to < 4; ++to) {
            #pragma unroll
            for (int e = 0; e < 4; ++e) {
                int i = to * 16 + g * 4 + e;
                if (i < 49) {
                    int nsp = nsp0 + (i / 7) * HWIMG + (i % 7);
                    unsigned short* ob = att + obase + (size_t)nsp * DIMC + head * HD;
                    #pragma unroll
                    for (int tn = 0; tn < 2; ++tn)
                        ob[tn * 16 + c] = f2bf(o[to][tn][e]);
                }
            }
        }
        // next head reuses Q/K/V regions; in-wave DS ordering + fences above protect
        asm volatile("s_waitcnt lgkmcnt(0)" ::: "memory");
    }
}

// ---------------- proj GEMM (R4-proven): C = w_proj @ att^T + bias, fp32 NCHW -------
__global__ __launch_bounds__(256) void gemm_proj(
    const unsigned short* __restrict__ A,     // [384][384] bf16
    const unsigned short* __restrict__ Bm,    // att [NROWS][384] spatial-major
    const float* __restrict__ bias,
    float* __restrict__ C)
{
    __shared__ char Al[128 * 128];
    __shared__ char Bl[128 * 128];
    const int tid = threadIdx.x;

    constexpr int MT = 3;
    const unsigned nwg = gridDim.x;
    const unsigned lin = blockIdx.x;
    const unsigned swz = (lin & 7) * (nwg >> 3) + (lin >> 3);
    const int m0 = (int)(swz % MT) * 128;
    const int ng0 = (int)(swz / MT) * 128;

    const int lane = tid & 63;
    const int wv = tid >> 6;
    const int wr = wv >> 1, wc = wv & 1;
    const int lrow = lane & 15, kgrp = lane >> 4;

    f32x4 acc[4][4] = {};

    const char* Abase = (const char*)(A + (size_t)m0 * KDIM);
    const char* Bbase = (const char*)(Bm + (size_t)ng0 * KDIM);

    for (int kt = 0; kt < KDIM / 64; ++kt) {
        const int kb = kt * 128;
        #pragma unroll
        for (int it = 0; it < 4; ++it) {
            int chunk = it * 256 + tid;
            int row = chunk >> 3, slot = chunk & 7;
            int scol = (slot ^ (row & 7)) * 16;
            __builtin_amdgcn_global_load_lds(
                (gas_ptr)(Abase + (size_t)row * (KDIM * 2) + kb + scol),
                (las_ptr)(Al + chunk * 16), 16, 0, 0);
        }
        #pragma unroll
        for (int it = 0; it < 4; ++it) {
            int chunk = it * 256 + tid;
            int row = chunk >> 3, slot = chunk & 7;
            int scol = (slot ^ (row & 7)) * 16;
            __builtin_amdgcn_global_load_lds(
                (gas_ptr)(Bbase + (size_t)row * (KDIM * 2) + kb + scol),
                (las_ptr)(Bl + chunk * 16), 16, 0, 0);
        }
        __syncthreads();
        #pragma unroll
        for (int kk = 0; kk < 2; ++kk) {
            short8 af[4], bfr[4];
            #pragma unroll
            for (int i = 0; i < 4; ++i) {
                int row = wr * 64 + i * 16 + lrow;
                int slot = (kk * 4 + kgrp) ^ (row & 7);
                af[i] = *(const short8*)(Al + row * 128 + slot * 16);
            }
            #pragma unroll
            for (int j = 0; j < 4; ++j) {
                int row = wc * 64 + j * 16 + lrow;
                int slot = (kk * 4 + kgrp) ^ (row & 7);
                bfr[j] = *(const short8*)(Bl + row * 128 + slot * 16);
            }
            __builtin_amdgcn_s_setprio(1);
            #pragma unroll
            for (int i = 0; i < 4; ++i)
                #pragma unroll
                for (int j = 0; j < 4; ++j)
                    acc[i][j] = __builtin_amdgcn_mfma_f32_16x16x32_bf16(af[i], bfr[j], acc[i][j], 0, 0, 0);
            __builtin_amdgcn_s_setprio(0);
        }
        __syncthreads();
    }

    #pragma unroll
    for (int i = 0; i < 4; ++i) {
        int m = m0 + wr * 64 + i * 16 + kgrp * 4;
        float b0 = bias[m + 0], b1 = bias[m + 1], b2 = bias[m + 2], b3 = bias[m + 3];
        #pragma unroll
        for (int j = 0; j < 4; ++j) {
            int ng = ng0 + wc * 64 + j * 16 + lrow;
            unsigned bb = (unsigned)ng / 3136u;
            unsigned nsp = (unsigned)ng - bb * 3136u;
            C[((size_t)bb * DIMC + m + 0) * 3136 + nsp] = acc[i][j].x + b0;
            C[((size_t)bb * DIMC + m + 1) * 3136 + nsp] = acc[i][j].y + b1;
            C[((size_t)bb * DIMC + m + 2) * 3136 + nsp] = acc[i][j].z + b2;
            C[((size_t)bb * DIMC + m + 3) * 3136 + nsp] = acc[i][j].w + b3;
        }
    }
}

extern "C" void kernel_launch(void* const* d_in, const int* in_sizes, int n_in,
                              void* d_out, int out_size, void* d_ws, size_t ws_size,
                              hipStream_t stream) {
    const float* x          = (const float*)d_in[0];
    const float* w_qkv      = (const float*)d_in[1];
    const float* w_proj     = (const float*)d_in[2];
    const float* b_proj     = (const float*)d_in[3];
    const float* bias_table = (const float*)d_in[4];
    const int*   rel_index  = (const int*)d_in[5];

    unsigned short* xt    = (unsigned short*)d_ws;               // [NROWS][384] win-gathered
    unsigned short* att   = xt + (size_t)NROWS * KDIM;           // [B*3136][384] spatial-major
    unsigned short* wqb   = att + (size_t)NROWS * KDIM;          // [1152][384]
    unsigned short* wpb   = wqb + QKV_M * KDIM;                  // [384][384]
    float*          biasp = (float*)(wpb + DIMC * KDIM);         // [12][64][64]

    cvt_w<<<(QKV_M * KDIM + 255) / 256, 256, 0, stream>>>(w_qkv, wqb, QKV_M * KDIM);
    cvt_w<<<(DIMC * KDIM + 255) / 256, 256, 0, stream>>>(w_proj, wpb, DIMC * KDIM);
    cvt_x<<<dim3(98, 12, BATCH), 256, 0, stream>>>(x, xt);
    fill_bias<<<192, 256, 0, stream>>>(bias_table, rel_index, biasp);

    // fused QKV + attention: 1 block per window
    fused_qkv_attn<<<NWIN, 256, 0, stream>>>(xt, wqb, biasp, att);

    // proj: 3 m-tiles x 784 n-tiles = 2352 blocks
    gemm_proj<<<2352, 256, 0, stream>>>(wpb, att, b_proj, (float*)d_out);
}

// Round 11
// 495.094 us; speedup vs baseline: 1.0723x; 1.0723x over previous
//
#include <hip/hip_runtime.h>

#define NH 12
#define HD 32
#define DIMC 384
#define BATCH 32
#define HWIMG 56
#define NWIN 2048          // 32 batches * 64 windows
#define NROWS 100352       // NWIN * 49, dense window-gathered rows
#define QKV_M 1152
#define KDIM 384
#define QSCALE 0.17677669529663687f

typedef __attribute__((ext_vector_type(8))) short short8;
typedef __attribute__((ext_vector_type(4))) short short4v;
typedef __attribute__((ext_vector_type(4))) float f32x4;

typedef const __attribute__((address_space(1))) unsigned int* gas_ptr;
typedef __attribute__((address_space(3))) unsigned int* las_ptr;

__device__ __forceinline__ unsigned short f2bf(float f) {
    union { float f; unsigned u; } v; v.f = f;
    unsigned r = v.u + 0x7FFF + ((v.u >> 16) & 1);
    return (unsigned short)(r >> 16);
}

// ---------------- fp32 -> bf16 weight convert ----------------
__global__ __launch_bounds__(256) void cvt_w(const float* __restrict__ in,
                                             unsigned short* __restrict__ out, int n) {
    int i = blockIdx.x * 256 + threadIdx.x;
    if (i < n) out[i] = f2bf(in[i]);
}

// ---------------- x [B,384,56,56] fp32 -> xt [NROWS,384] bf16 (window-gathered) -------
__global__ __launch_bounds__(256) void cvt_x(const float* __restrict__ x,
                                             unsigned short* __restrict__ xt) {
    __shared__ float tile[32][33];
    const int b = blockIdx.z, c0 = blockIdx.y * 32, n0 = blockIdx.x * 32;
    const int tid = threadIdx.x;
    const int cl = tid >> 5, nl = tid & 31;
    #pragma unroll
    for (int p = 0; p < 4; ++p)
        tile[cl + p * 8][nl] = x[((size_t)b * DIMC + c0 + cl + p * 8) * 3136 + n0 + nl];
    __syncthreads();
    const int nl2 = tid >> 3, cq = (tid & 7) * 4;
    const int n = n0 + nl2;
    const int nh = n / HWIMG, nw = n % HWIMG;
    const int row = ((b * 64 + (nh / 7) * 8 + nw / 7) * 49 + (nh % 7) * 7 + nw % 7);
    short4v pk;
    #pragma unroll
    for (int u = 0; u < 4; ++u) pk[u] = (short)f2bf(tile[cq + u][nl2]);
    *(short4v*)(xt + (size_t)row * KDIM + c0 + cq) = pk;
}

// ---------------- bias expand: biasp[h][j:64][i:64] fp32, transposed & padded ----------
__global__ __launch_bounds__(256) void fill_bias(const float* __restrict__ bias_table,
                                                 const int* __restrict__ rel_index,
                                                 float* __restrict__ biasp) {
    int id = blockIdx.x * 256 + threadIdx.x;   // 12*4096
    int h = id >> 12, r = id & 4095;
    int j = r >> 6, i = r & 63;
    float v = 0.f;
    if (i < 49 && j < 49) v = bias_table[rel_index[i * 49 + j] * NH + h];
    biasp[id] = v;
}

// ---------------- zero the j-pad of vw ----------------
__global__ __launch_bounds__(256) void zero_vpad(unsigned short* __restrict__ vw) {
    int r = blockIdx.x * 256 + threadIdx.x;    // 2048*384 rows
    unsigned short* p = vw + (size_t)r * 64;
    p[49] = 0;
    unsigned* p4 = (unsigned*)(p + 50);
    #pragma unroll
    for (int u = 0; u < 7; ++u) p4[u] = 0;
}

// ---------------- bf16 MFMA GEMM, 128m x 256n tile, 64 MFMA per wave per barrier ------
// C[m, ng] = sum_k A[m,k] * Bm[ng,k].  1-D grid, XCD-partitioned, m-fastest.
// R4-proven 2-barrier loop; wave tile 64m x 128n (acc 4x8 f32x4).
// MODE 0 (QKV): m<768 -> qkw[ng*768+m] bf16 (m<384 scaled by QSCALE);
//               m>=768 -> vw[(ng/49)*24576 + (m-768)*64 + ng%49] bf16
// MODE 1 (proj): fp32 NCHW + bias; B rows are spatial-major (ng = b*3136+nsp)
template<int MODE>
__global__ __launch_bounds__(256) void gemm_mfma(
    const unsigned short* __restrict__ A,
    const unsigned short* __restrict__ Bm,
    const float* __restrict__ bias,
    void* __restrict__ Cout,
    unsigned short* __restrict__ Cv)
{
    __shared__ char Al[128 * 128];   // 128 m-rows x 128B (64 bf16 k), XOR-swizzled
    __shared__ char Bl[256 * 128];   // 256 n-rows x 128B
    const int tid = threadIdx.x;

    constexpr int MT = (MODE == 0) ? 9 : 3;   // 128-row m-tiles
    const unsigned nwg = gridDim.x;
    const unsigned lin = blockIdx.x;
    const unsigned swz = (lin & 7) * (nwg >> 3) + (lin >> 3);  // XCD-contiguous
    const int m0 = (int)(swz % MT) * 128;
    const int ng0 = (int)(swz / MT) * 256;

    const int lane = tid & 63;
    const int wv = tid >> 6;
    const int wr = wv >> 1, wc = wv & 1;       // wave tile: 64m x 128n
    const int lrow = lane & 15, kgrp = lane >> 4;

    f32x4 acc[4][8] = {};

    const char* Abase = (const char*)(A + (size_t)m0 * KDIM);
    const char* Bbase = (const char*)(Bm + (size_t)ng0 * KDIM);

    for (int kt = 0; kt < KDIM / 64; ++kt) {
        const int kb = kt * 128;
        // stage A: 1024 16B chunks (4/thread)
        #pragma unroll
        for (int it = 0; it < 4; ++it) {
            int chunk = it * 256 + tid;
            int row = chunk >> 3, slot = chunk & 7;
            int scol = (slot ^ (row & 7)) * 16;
            __builtin_amdgcn_global_load_lds(
                (gas_ptr)(Abase + (size_t)row * (KDIM * 2) + kb + scol),
                (las_ptr)(Al + chunk * 16), 16, 0, 0);
        }
        // stage B: 2048 16B chunks (8/thread)
        #pragma unroll
        for (int it = 0; it < 8; ++it) {
            int chunk = it * 256 + tid;
            int row = chunk >> 3, slot = chunk & 7;
            int scol = (slot ^ (row & 7)) * 16;
            __builtin_amdgcn_global_load_lds(
                (gas_ptr)(Bbase + (size_t)row * (KDIM * 2) + kb + scol),
                (las_ptr)(Bl + chunk * 16), 16, 0, 0);
        }
        __syncthreads();
        #pragma unroll
        for (int kk = 0; kk < 2; ++kk) {
            short8 af[4], bfr[8];
            #pragma unroll
            for (int i = 0; i < 4; ++i) {
                int row = wr * 64 + i * 16 + lrow;
                int slot = (kk * 4 + kgrp) ^ (row & 7);
                af[i] = *(const short8*)(Al + row * 128 + slot * 16);
            }
            #pragma unroll
            for (int j = 0; j < 8; ++j) {
                int row = wc * 128 + j * 16 + lrow;
                int slot = (kk * 4 + kgrp) ^ (row & 7);
                bfr[j] = *(const short8*)(Bl + row * 128 + slot * 16);
            }
            __builtin_amdgcn_s_setprio(1);
            #pragma unroll
            for (int i = 0; i < 4; ++i)
                #pragma unroll
                for (int j = 0; j < 8; ++j)
                    acc[i][j] = __builtin_amdgcn_mfma_f32_16x16x32_bf16(af[i], bfr[j], acc[i][j], 0, 0, 0);
            __builtin_amdgcn_s_setprio(0);
        }
        __syncthreads();
    }

    if (MODE == 0) {
        unsigned short* qk = (unsigned short*)Cout;
        const float sc = (m0 < 384) ? QSCALE : 1.0f;
        #pragma unroll
        for (int i = 0; i < 4; ++i) {
            int m = m0 + wr * 64 + i * 16 + kgrp * 4;
            #pragma unroll
            for (int j = 0; j < 8; ++j) {
                int ng = ng0 + wc * 128 + j * 16 + lrow;
                if (m < 768) {
                    short4v pk;
                    pk.x = (short)f2bf(acc[i][j].x * sc);
                    pk.y = (short)f2bf(acc[i][j].y * sc);
                    pk.z = (short)f2bf(acc[i][j].z * sc);
                    pk.w = (short)f2bf(acc[i][j].w * sc);
                    *(short4v*)(qk + (size_t)ng * 768 + m) = pk;
                } else {
                    unsigned win = (unsigned)ng / 49u;
                    unsigned ii = (unsigned)ng - win * 49u;
                    unsigned short* vb = Cv + (size_t)win * 24576 + (size_t)(m - 768) * 64 + ii;
                    vb[0]   = f2bf(acc[i][j].x);
                    vb[64]  = f2bf(acc[i][j].y);
                    vb[128] = f2bf(acc[i][j].z);
                    vb[192] = f2bf(acc[i][j].w);
                }
            }
        }
    } else {
        float* C = (float*)Cout;
        #pragma unroll
        for (int i = 0; i < 4; ++i) {
            int m = m0 + wr * 64 + i * 16 + kgrp * 4;
            float b0 = bias[m + 0], b1 = bias[m + 1], b2 = bias[m + 2], b3 = bias[m + 3];
            #pragma unroll
            for (int j = 0; j < 8; ++j) {
                int ng = ng0 + wc * 128 + j * 16 + lrow;
                unsigned bb = (unsigned)ng / 3136u;
                unsigned nsp = (unsigned)ng - bb * 3136u;
                C[((size_t)bb * DIMC + m + 0) * 3136 + nsp] = acc[i][j].x + b0;
                C[((size_t)bb * DIMC + m + 1) * 3136 + nsp] = acc[i][j].y + b1;
                C[((size_t)bb * DIMC + m + 2) * 3136 + nsp] = acc[i][j].z + b2;
                C[((size_t)bb * DIMC + m + 3) * 3136 + nsp] = acc[i][j].w + b3;
            }
        }
    }
}

// ---------------- MFMA windowed attention: one wave per (window, head), no LDS -------
// Output att is SPATIAL-major: row = b*3136 + nsp  (so GEMM2 stores coalesce)
__global__ __launch_bounds__(256) void win_attn(
    const unsigned short* __restrict__ qkw,   // [NROWS][768], q pre-scaled, win-major
    const unsigned short* __restrict__ vw,    // [NWIN][384][64]
    const float* __restrict__ biasp,          // [12][64][64]  (j-major, transposed)
    unsigned short* __restrict__ att)         // [B*3136][384] spatial-major
{
    const int tid = threadIdx.x;
    const int lane = tid & 63;
    const int g = lane >> 4, c = lane & 15;
    const int bid = blockIdx.x;
    const int swz = (bid & 7) * 768 + (bid >> 3);       // 6144 blocks
    const int W = swz * 4 + (tid >> 6);
    const int win = W / 12;
    const int head = W - win * 12;

    const unsigned short* qbase = qkw + (size_t)win * 49 * 768 + head * HD;

    short8 kf[4], qf[4];
    #pragma unroll
    for (int a = 0; a < 4; ++a) {
        int r = a * 16 + c; if (r > 48) r = 48;
        kf[a] = *(const short8*)(qbase + (size_t)r * 768 + DIMC + g * 8);
        qf[a] = *(const short8*)(qbase + (size_t)r * 768 + g * 8);
    }

    // S^T fragments: rows j = a*16+g*4+e, cols i = bi*16+c
    f32x4 s[4][4] = {};
    #pragma unroll
    for (int a = 0; a < 4; ++a)
        #pragma unroll
        for (int bi = 0; bi < 4; ++bi)
            s[a][bi] = __builtin_amdgcn_mfma_f32_16x16x32_bf16(kf[a], qf[bi], s[a][bi], 0, 0, 0);

    const float* bp = biasp + head * 4096;
    #pragma unroll
    for (int bi = 0; bi < 4; ++bi) {
        float mx = -1e30f;
        #pragma unroll
        for (int a = 0; a < 4; ++a) {
            #pragma unroll
            for (int e = 0; e < 4; ++e) {
                int j = a * 16 + g * 4 + e;
                float sv = s[a][bi][e] + bp[j * 64 + bi * 16 + c];
                sv = (j < 49) ? sv : -1e30f;
                s[a][bi][e] = sv;
                mx = fmaxf(mx, sv);
            }
        }
        mx = fmaxf(mx, __shfl_xor(mx, 16));
        mx = fmaxf(mx, __shfl_xor(mx, 32));
        float sum = 0.f;
        #pragma unroll
        for (int a = 0; a < 4; ++a) {
            #pragma unroll
            for (int e = 0; e < 4; ++e) {
                int j = a * 16 + g * 4 + e;
                float pv = (j < 49) ? __expf(s[a][bi][e] - mx) : 0.f;
                s[a][bi][e] = pv;
                sum += pv;
            }
        }
        sum += __shfl_xor(sum, 16);
        sum += __shfl_xor(sum, 32);
        float inv = 1.0f / sum;
        #pragma unroll
        for (int a = 0; a < 4; ++a)
            #pragma unroll
            for (int e = 0; e < 4; ++e)
                s[a][bi][e] *= inv;
    }

    unsigned pk[4][4][2];
    #pragma unroll
    for (int a = 0; a < 4; ++a)
        #pragma unroll
        for (int bi = 0; bi < 4; ++bi)
            #pragma unroll
            for (int h = 0; h < 2; ++h)
                pk[a][bi][h] = (unsigned)f2bf(s[a][bi][2 * h]) |
                               ((unsigned)f2bf(s[a][bi][2 * h + 1]) << 16);

    const unsigned short* vbase = vw + (size_t)win * 24576 + head * HD * 64;
    short8 vf[2][2];
    #pragma unroll
    for (int tn = 0; tn < 2; ++tn)
        #pragma unroll
        for (int ks = 0; ks < 2; ++ks)
            vf[tn][ks] = *(const short8*)(vbase + (tn * 16 + c) * 64 + ks * 32 + g * 8);

    f32x4 o[4][2] = {};
    const int gsel = g >> 1;
    const int sgb = 2 * (g & 1);
    #pragma unroll
    for (int ks = 0; ks < 2; ++ks) {
        #pragma unroll
        for (int to = 0; to < 4; ++to) {
            union { int w[4]; short8 v; } u;
            #pragma unroll
            for (int w = 0; w < 4; ++w) {
                int srcl = ((sgb + (w >> 1)) * 16 + c) << 2;
                int rA = __builtin_amdgcn_ds_bpermute(srcl, (int)pk[ks * 2 + 0][to][w & 1]);
                int rB = __builtin_amdgcn_ds_bpermute(srcl, (int)pk[ks * 2 + 1][to][w & 1]);
                u.w[w] = gsel ? rB : rA;
            }
            #pragma unroll
            for (int tn = 0; tn < 2; ++tn)
                o[to][tn] = __builtin_amdgcn_mfma_f32_16x16x32_bf16(u.v, vf[tn][ks], o[to][tn], 0, 0, 0);
        }
    }

    // store O rows i = to*16+g*4+e (i<49), cols d = tn*16+c, to spatial-major att
    const int wl = win & 63, bb = win >> 6;
    const size_t obase = (size_t)bb * 3136 * DIMC;
    const int nsp0 = (wl >> 3) * 7 * HWIMG + (wl & 7) * 7;
    #pragma unroll
    for (int to = 0; to < 4; ++to) {
        #pragma unroll
        for (int e = 0; e < 4; ++e) {
            int i = to * 16 + g * 4 + e;
            if (i < 49) {
                int nsp = nsp0 + (i / 7) * HWIMG + (i % 7);
                unsigned short* ob = att + obase + (size_t)nsp * DIMC + head * HD;
                #pragma unroll
                for (int tn = 0; tn < 2; ++tn)
                    ob[tn * 16 + c] = f2bf(o[to][tn][e]);
            }
        }
    }
}

extern "C" void kernel_launch(void* const* d_in, const int* in_sizes, int n_in,
                              void* d_out, int out_size, void* d_ws, size_t ws_size,
                              hipStream_t stream) {
    const float* x          = (const float*)d_in[0];
    const float* w_qkv      = (const float*)d_in[1];
    const float* w_proj     = (const float*)d_in[2];
    const float* b_proj     = (const float*)d_in[3];
    const float* bias_table = (const float*)d_in[4];
    const int*   rel_index  = (const int*)d_in[5];

    // workspace layout (att aliases xt: xt consumed by GEMM1 before att is written)
    unsigned short* xt   = (unsigned short*)d_ws;                    // [NROWS][384]
    unsigned short* att  = xt;                                       // alias, spatial-major
    unsigned short* qkw  = xt + (size_t)NROWS * KDIM;                // [NROWS][768]
    unsigned short* vw   = qkw + (size_t)NROWS * 768;                // [NWIN][384][64]
    unsigned short* wqb  = vw + (size_t)NWIN * 384 * 64;             // [1152][384]
    unsigned short* wpb  = wqb + QKV_M * KDIM;                       // [384][384]
    float*          biasp = (float*)(wpb + DIMC * KDIM);             // [12][64][64]

    cvt_w<<<(QKV_M * KDIM + 255) / 256, 256, 0, stream>>>(w_qkv, wqb, QKV_M * KDIM);
    cvt_w<<<(DIMC * KDIM + 255) / 256, 256, 0, stream>>>(w_proj, wpb, DIMC * KDIM);
    cvt_x<<<dim3(98, 12, BATCH), 256, 0, stream>>>(x, xt);
    fill_bias<<<192, 256, 0, stream>>>(bias_table, rel_index, biasp);
    zero_vpad<<<3072, 256, 0, stream>>>(vw);

    // GEMM1: 9 m-tiles x 392 n-tiles (256-wide) = 3528 blocks (1-D, XCD-supertiled)
    gemm_mfma<0><<<3528, 256, 0, stream>>>(wqb, xt, nullptr, (void*)qkw, vw);

    // attention: 24576 (win,head) waves, 4 per block
    win_attn<<<6144, 256, 0, stream>>>(qkw, vw, biasp, att);

    // GEMM2: 3 m-tiles x 392 n-tiles = 1176 blocks; spatial-major B, coalesced NCHW out
    gemm_mfma<1><<<1176, 256, 0, stream>>>(wpb, att, b_proj, (void*)d_out, nullptr);
}

// Round 12
// 410.531 us; speedup vs baseline: 1.2931x; 1.2060x over previous
//
#include <hip/hip_runtime.h>

#define NH 12
#define HD 32
#define DIMC 384
#define BATCH 32
#define HWIMG 56
#define NWIN 2048          // 32 batches * 64 windows
#define NROWS 100352       // NWIN * 49, dense window-gathered rows
#define QKV_M 1152
#define MPAD 1280          // 5 x 256 m-tiles (rows 1152-1279 are zero pad)
#define KDIM 384
#define QSCALE 0.17677669529663687f

typedef __attribute__((ext_vector_type(8))) short short8;
typedef __attribute__((ext_vector_type(4))) short short4v;
typedef __attribute__((ext_vector_type(4))) float f32x4;

typedef const __attribute__((address_space(1))) unsigned int* gas_ptr;
typedef __attribute__((address_space(3))) unsigned int* las_ptr;

__device__ __forceinline__ unsigned short f2bf(float f) {
    union { float f; unsigned u; } v; v.f = f;
    unsigned r = v.u + 0x7FFF + ((v.u >> 16) & 1);
    return (unsigned short)(r >> 16);
}

// ---------------- fp32 -> bf16 weight convert (with zero tail pad) ----------------
__global__ __launch_bounds__(256) void cvt_w(const float* __restrict__ in,
                                             unsigned short* __restrict__ out,
                                             int n_real, int n_total) {
    int i = blockIdx.x * 256 + threadIdx.x;
    if (i < n_total) out[i] = (i < n_real) ? f2bf(in[i]) : (unsigned short)0;
}

// ---------------- x [B,384,56,56] fp32 -> xt [NROWS,384] bf16 (window-gathered) -------
__global__ __launch_bounds__(256) void cvt_x(const float* __restrict__ x,
                                             unsigned short* __restrict__ xt) {
    __shared__ float tile[32][33];
    const int b = blockIdx.z, c0 = blockIdx.y * 32, n0 = blockIdx.x * 32;
    const int tid = threadIdx.x;
    const int cl = tid >> 5, nl = tid & 31;
    #pragma unroll
    for (int p = 0; p < 4; ++p)
        tile[cl + p * 8][nl] = x[((size_t)b * DIMC + c0 + cl + p * 8) * 3136 + n0 + nl];
    __syncthreads();
    const int nl2 = tid >> 3, cq = (tid & 7) * 4;
    const int n = n0 + nl2;
    const int nh = n / HWIMG, nw = n % HWIMG;
    const int row = ((b * 64 + (nh / 7) * 8 + nw / 7) * 49 + (nh % 7) * 7 + nw % 7);
    short4v pk;
    #pragma unroll
    for (int u = 0; u < 4; ++u) pk[u] = (short)f2bf(tile[cq + u][nl2]);
    *(short4v*)(xt + (size_t)row * KDIM + c0 + cq) = pk;
}

// ---------------- bias expand: biasp[h][j:64][i:64] fp32, transposed & padded ----------
__global__ __launch_bounds__(256) void fill_bias(const float* __restrict__ bias_table,
                                                 const int* __restrict__ rel_index,
                                                 float* __restrict__ biasp) {
    int id = blockIdx.x * 256 + threadIdx.x;   // 12*4096
    int h = id >> 12, r = id & 4095;
    int j = r >> 6, i = r & 63;
    float v = 0.f;
    if (i < 49 && j < 49) v = bias_table[rel_index[i * 49 + j] * NH + h];
    biasp[id] = v;
}

// ---------------- zero the j-pad of vw ----------------
__global__ __launch_bounds__(256) void zero_vpad(unsigned short* __restrict__ vw) {
    int r = blockIdx.x * 256 + threadIdx.x;    // 2048*384 rows
    unsigned short* p = vw + (size_t)r * 64;
    p[49] = 0;
    unsigned* p4 = (unsigned*)(p + 50);
    #pragma unroll
    for (int u = 0; u < 7; ++u) p4[u] = 0;
}

// ============ GEMM1: 8-phase 256x256 bf16 MFMA (faithful fine-interleave port) ========
// 512 threads / 8 waves (2M x 4N), per-wave 128x64, BK=64, K=384 (6 K-tiles).
// LDS 128KB = dbuf[2] x {A0,A1,B0,B1} x 16KB.  Per K-tile: 4 phases (quadrants
// (0,0),(0,1),(1,1),(1,0)); each phase stages ONE half of KT t+1 into the other
// dbuf, reads its fragment subtile, runs 16 setprio'd MFMA, trailing barrier.
// Counted vmcnt(2) once per K-tile (phase 0) + barrier gates the new K-tile.
// Output: m<768 -> qkw[ng*768+m] (q scaled); 768<=m<1152 -> vw; m>=1152 skipped.
__global__ __launch_bounds__(512, 2) void gemm_qkv8(
    const unsigned short* __restrict__ A,    // wq_pad [1280][384]
    const unsigned short* __restrict__ Bm,   // xt [NROWS][384]
    unsigned short* __restrict__ qk,         // qkw [NROWS][768]
    unsigned short* __restrict__ Cv)         // vw  [NWIN][384][64]
{
    __shared__ char L[2][65536];
    const int tid = threadIdx.x;

    const unsigned nwg = gridDim.x, lin = blockIdx.x;          // 1960 (%8==0)
    const unsigned swz = (lin & 7) * (nwg >> 3) + (lin >> 3);  // XCD-contiguous
    const int m0 = (int)(swz % 5) * 256;                       // m-fastest
    const int ng0 = (int)(swz / 5) * 256;

    const int lane = tid & 63;
    const int wv = tid >> 6;          // 0-7
    const int wr = wv >> 2;           // A-half owned by this wave
    const int wc = wv & 3;            // 64-col group; B-half = wc>>1
    const int lrow = lane & 15, kgrp = lane >> 4;

    const char* Ab = (const char*)(A + (size_t)m0 * KDIM);
    const char* Bb = (const char*)(Bm + (size_t)ng0 * KDIM);

    const int c0 = tid, c1 = tid + 512;   // 2 of 1024 16B chunks per half

    auto stage_half = [&](int t, int h, int buf) {
        const char* src = (h < 2) ? (Ab + (size_t)((h & 1) * 128) * 768)
                                  : (Bb + (size_t)((h & 1) * 128) * 768);
        const int kb = t * 128;
        char* dst = (char*)L[buf] + h * 16384;
        int row0 = c0 >> 3, slot0 = c0 & 7;
        int sc0 = (slot0 ^ (row0 & 7)) * 16;
        __builtin_amdgcn_global_load_lds((gas_ptr)(src + (size_t)row0 * 768 + kb + sc0),
                                         (las_ptr)(dst + c0 * 16), 16, 0, 0);
        int row1 = c1 >> 3, slot1 = c1 & 7;
        int sc1 = (slot1 ^ (row1 & 7)) * 16;
        __builtin_amdgcn_global_load_lds((gas_ptr)(src + (size_t)row1 * 768 + kb + sc1),
                                         (las_ptr)(dst + c1 * 16), 16, 0, 0);
    };

    // prologue: KT0 -> dbuf 0, full drain
    stage_half(0, 0, 0); stage_half(0, 1, 0); stage_half(0, 2, 0); stage_half(0, 3, 0);
    asm volatile("s_waitcnt vmcnt(0)" ::: "memory");
    __builtin_amdgcn_s_barrier();

    f32x4 acc[8][4] = {};
    short8 af[4][2], bfr[2][2];

    auto phase = [&](int buf, int qm, int qn, bool rdA, bool rdB) {
        if (rdA) {
            #pragma unroll
            for (int i = 0; i < 4; ++i) {
                int row = qm * 64 + i * 16 + lrow;
                #pragma unroll
                for (int kk = 0; kk < 2; ++kk) {
                    int slot = (kk * 4 + kgrp) ^ (row & 7);
                    af[i][kk] = *(const short8*)((char*)L[buf] + wr * 16384 + row * 128 + slot * 16);
                }
            }
        }
        if (rdB) {
            #pragma unroll
            for (int j = 0; j < 2; ++j) {
                int row = (wc & 1) * 64 + qn * 32 + j * 16 + lrow;
                #pragma unroll
                for (int kk = 0; kk < 2; ++kk) {
                    int slot = (kk * 4 + kgrp) ^ (row & 7);
                    bfr[j][kk] = *(const short8*)((char*)L[buf] + (2 + (wc >> 1)) * 16384 + row * 128 + slot * 16);
                }
            }
        }
        __builtin_amdgcn_s_setprio(1);
        #pragma unroll
        for (int kk = 0; kk < 2; ++kk)
            #pragma unroll
            for (int i = 0; i < 4; ++i)
                #pragma unroll
                for (int j = 0; j < 2; ++j)
                    acc[qm * 4 + i][qn * 2 + j] = __builtin_amdgcn_mfma_f32_16x16x32_bf16(
                        af[i][kk], bfr[j][kk], acc[qm * 4 + i][qn * 2 + j], 0, 0, 0);
        __builtin_amdgcn_s_setprio(0);
        __builtin_amdgcn_s_barrier();
    };

    for (int t = 0; t < 6; ++t) {
        const int buf = t & 1, nbuf = buf ^ 1;
        // phase 0: stage A0(t+1); counted vmcnt gates KT t; barrier makes it block-wide
        if (t < 5) {
            stage_half(t + 1, 0, nbuf);
            asm volatile("s_waitcnt vmcnt(2)" ::: "memory");
        } else {
            asm volatile("s_waitcnt vmcnt(0)" ::: "memory");
        }
        __builtin_amdgcn_s_barrier();
        phase(buf, 0, 0, true, true);
        // phase 1: stage A1(t+1)
        if (t < 5) stage_half(t + 1, 1, nbuf);
        phase(buf, 0, 1, false, true);
        // phase 2: stage B0(t+1)
        if (t < 5) stage_half(t + 1, 2, nbuf);
        phase(buf, 1, 1, true, false);
        // phase 3: stage B1(t+1)
        if (t < 5) stage_half(t + 1, 3, nbuf);
        phase(buf, 1, 0, false, true);
    }

    // ---- epilogue ----
    #pragma unroll
    for (int mi = 0; mi < 8; ++mi) {
        int m = m0 + wr * 128 + mi * 16 + kgrp * 4;
        if (m >= QKV_M) continue;          // zero-pad tail of m-tile 4
        const float sc = (m < 384) ? QSCALE : 1.0f;
        #pragma unroll
        for (int ni = 0; ni < 4; ++ni) {
            int ng = ng0 + wc * 64 + ni * 16 + lrow;
            f32x4 a = acc[mi][ni];
            if (m < 768) {
                short4v pk;
                pk.x = (short)f2bf(a.x * sc);
                pk.y = (short)f2bf(a.y * sc);
                pk.z = (short)f2bf(a.z * sc);
                pk.w = (short)f2bf(a.w * sc);
                *(short4v*)(qk + (size_t)ng * 768 + m) = pk;
            } else {
                unsigned win = (unsigned)ng / 49u;
                unsigned ii = (unsigned)ng - win * 49u;
                unsigned short* vb = Cv + (size_t)win * 24576 + (size_t)(m - 768) * 64 + ii;
                vb[0]   = f2bf(a.x);
                vb[64]  = f2bf(a.y);
                vb[128] = f2bf(a.z);
                vb[192] = f2bf(a.w);
            }
        }
    }
}

// ---------------- proj GEMM (R4-proven): C = w_proj @ att^T + bias, fp32 NCHW -------
__global__ __launch_bounds__(256) void gemm_proj(
    const unsigned short* __restrict__ A,     // [384][384] bf16
    const unsigned short* __restrict__ Bm,    // att [NROWS][384] spatial-major
    const float* __restrict__ bias,
    float* __restrict__ C)
{
    __shared__ char Al[128 * 128];
    __shared__ char Bl[128 * 128];
    const int tid = threadIdx.x;

    constexpr int MT = 3;
    const unsigned nwg = gridDim.x;
    const unsigned lin = blockIdx.x;
    const unsigned swz = (lin & 7) * (nwg >> 3) + (lin >> 3);
    const int m0 = (int)(swz % MT) * 128;
    const int ng0 = (int)(swz / MT) * 128;

    const int lane = tid & 63;
    const int wv = tid >> 6;
    const int wr = wv >> 1, wc = wv & 1;
    const int lrow = lane & 15, kgrp = lane >> 4;

    f32x4 acc[4][4] = {};

    const char* Abase = (const char*)(A + (size_t)m0 * KDIM);
    const char* Bbase = (const char*)(Bm + (size_t)ng0 * KDIM);

    for (int kt = 0; kt < KDIM / 64; ++kt) {
        const int kb = kt * 128;
        #pragma unroll
        for (int it = 0; it < 4; ++it) {
            int chunk = it * 256 + tid;
            int row = chunk >> 3, slot = chunk & 7;
            int scol = (slot ^ (row & 7)) * 16;
            __builtin_amdgcn_global_load_lds(
                (gas_ptr)(Abase + (size_t)row * (KDIM * 2) + kb + scol),
                (las_ptr)(Al + chunk * 16), 16, 0, 0);
        }
        #pragma unroll
        for (int it = 0; it < 4; ++it) {
            int chunk = it * 256 + tid;
            int row = chunk >> 3, slot = chunk & 7;
            int scol = (slot ^ (row & 7)) * 16;
            __builtin_amdgcn_global_load_lds(
                (gas_ptr)(Bbase + (size_t)row * (KDIM * 2) + kb + scol),
                (las_ptr)(Bl + chunk * 16), 16, 0, 0);
        }
        __syncthreads();
        #pragma unroll
        for (int kk = 0; kk < 2; ++kk) {
            short8 af[4], bfr[4];
            #pragma unroll
            for (int i = 0; i < 4; ++i) {
                int row = wr * 64 + i * 16 + lrow;
                int slot = (kk * 4 + kgrp) ^ (row & 7);
                af[i] = *(const short8*)(Al + row * 128 + slot * 16);
            }
            #pragma unroll
            for (int j = 0; j < 4; ++j) {
                int row = wc * 64 + j * 16 + lrow;
                int slot = (kk * 4 + kgrp) ^ (row & 7);
                bfr[j] = *(const short8*)(Bl + row * 128 + slot * 16);
            }
            __builtin_amdgcn_s_setprio(1);
            #pragma unroll
            for (int i = 0; i < 4; ++i)
                #pragma unroll
                for (int j = 0; j < 4; ++j)
                    acc[i][j] = __builtin_amdgcn_mfma_f32_16x16x32_bf16(af[i], bfr[j], acc[i][j], 0, 0, 0);
            __builtin_amdgcn_s_setprio(0);
        }
        __syncthreads();
    }

    #pragma unroll
    for (int i = 0; i < 4; ++i) {
        int m = m0 + wr * 64 + i * 16 + kgrp * 4;
        float b0 = bias[m + 0], b1 = bias[m + 1], b2 = bias[m + 2], b3 = bias[m + 3];
        #pragma unroll
        for (int j = 0; j < 4; ++j) {
            int ng = ng0 + wc * 64 + j * 16 + lrow;
            unsigned bb = (unsigned)ng / 3136u;
            unsigned nsp = (unsigned)ng - bb * 3136u;
            C[((size_t)bb * DIMC + m + 0) * 3136 + nsp] = acc[i][j].x + b0;
            C[((size_t)bb * DIMC + m + 1) * 3136 + nsp] = acc[i][j].y + b1;
            C[((size_t)bb * DIMC + m + 2) * 3136 + nsp] = acc[i][j].z + b2;
            C[((size_t)bb * DIMC + m + 3) * 3136 + nsp] = acc[i][j].w + b3;
        }
    }
}

// ---------------- MFMA windowed attention: one wave per (window, head), no LDS -------
// Output att is SPATIAL-major: row = b*3136 + nsp  (so GEMM2 stores coalesce)
__global__ __launch_bounds__(256) void win_attn(
    const unsigned short* __restrict__ qkw,   // [NROWS][768], q pre-scaled, win-major
    const unsigned short* __restrict__ vw,    // [NWIN][384][64]
    const float* __restrict__ biasp,          // [12][64][64]  (j-major, transposed)
    unsigned short* __restrict__ att)         // [B*3136][384] spatial-major
{
    const int tid = threadIdx.x;
    const int lane = tid & 63;
    const int g = lane >> 4, c = lane & 15;
    const int bid = blockIdx.x;
    const int swz = (bid & 7) * 768 + (bid >> 3);       // 6144 blocks
    const int W = swz * 4 + (tid >> 6);
    const int win = W / 12;
    const int head = W - win * 12;

    const unsigned short* qbase = qkw + (size_t)win * 49 * 768 + head * HD;

    short8 kf[4], qf[4];
    #pragma unroll
    for (int a = 0; a < 4; ++a) {
        int r = a * 16 + c; if (r > 48) r = 48;
        kf[a] = *(const short8*)(qbase + (size_t)r * 768 + DIMC + g * 8);
        qf[a] = *(const short8*)(qbase + (size_t)r * 768 + g * 8);
    }

    // S^T fragments: rows j = a*16+g*4+e, cols i = bi*16+c
    f32x4 s[4][4] = {};
    #pragma unroll
    for (int a = 0; a < 4; ++a)
        #pragma unroll
        for (int bi = 0; bi < 4; ++bi)
            s[a][bi] = __builtin_amdgcn_mfma_f32_16x16x32_bf16(kf[a], qf[bi], s[a][bi], 0, 0, 0);

    const float* bp = biasp + head * 4096;
    #pragma unroll
    for (int bi = 0; bi < 4; ++bi) {
        float mx = -1e30f;
        #pragma unroll
        for (int a = 0; a < 4; ++a) {
            #pragma unroll
            for (int e = 0; e < 4; ++e) {
                int j = a * 16 + g * 4 + e;
                float sv = s[a][bi][e] + bp[j * 64 + bi * 16 + c];
                sv = (j < 49) ? sv : -1e30f;
                s[a][bi][e] = sv;
                mx = fmaxf(mx, sv);
            }
        }
        mx = fmaxf(mx, __shfl_xor(mx, 16));
        mx = fmaxf(mx, __shfl_xor(mx, 32));
        float sum = 0.f;
        #pragma unroll
        for (int a = 0; a < 4; ++a) {
            #pragma unroll
            for (int e = 0; e < 4; ++e) {
                int j = a * 16 + g * 4 + e;
                float pv = (j < 49) ? __expf(s[a][bi][e] - mx) : 0.f;
                s[a][bi][e] = pv;
                sum += pv;
            }
        }
        sum += __shfl_xor(sum, 16);
        sum += __shfl_xor(sum, 32);
        float inv = 1.0f / sum;
        #pragma unroll
        for (int a = 0; a < 4; ++a)
            #pragma unroll
            for (int e = 0; e < 4; ++e)
                s[a][bi][e] *= inv;
    }

    unsigned pk[4][4][2];
    #pragma unroll
    for (int a = 0; a < 4; ++a)
        #pragma unroll
        for (int bi = 0; bi < 4; ++bi)
            #pragma unroll
            for (int h = 0; h < 2; ++h)
                pk[a][bi][h] = (unsigned)f2bf(s[a][bi][2 * h]) |
                               ((unsigned)f2bf(s[a][bi][2 * h + 1]) << 16);

    const unsigned short* vbase = vw + (size_t)win * 24576 + head * HD * 64;
    short8 vf[2][2];
    #pragma unroll
    for (int tn = 0; tn < 2; ++tn)
        #pragma unroll
        for (int ks = 0; ks < 2; ++ks)
            vf[tn][ks] = *(const short8*)(vbase + (tn * 16 + c) * 64 + ks * 32 + g * 8);

    f32x4 o[4][2] = {};
    const int gsel = g >> 1;
    const int sgb = 2 * (g & 1);
    #pragma unroll
    for (int ks = 0; ks < 2; ++ks) {
        #pragma unroll
        for (int to = 0; to < 4; ++to) {
            union { int w[4]; short8 v; } u;
            #pragma unroll
            for (int w = 0; w < 4; ++w) {
                int srcl = ((sgb + (w >> 1)) * 16 + c) << 2;
                int rA = __builtin_amdgcn_ds_bpermute(srcl, (int)pk[ks * 2 + 0][to][w & 1]);
                int rB = __builtin_amdgcn_ds_bpermute(srcl, (int)pk[ks * 2 + 1][to][w & 1]);
                u.w[w] = gsel ? rB : rA;
            }
            #pragma unroll
            for (int tn = 0; tn < 2; ++tn)
                o[to][tn] = __builtin_amdgcn_mfma_f32_16x16x32_bf16(u.v, vf[tn][ks], o[to][tn], 0, 0, 0);
        }
    }

    // store O rows i = to*16+g*4+e (i<49), cols d = tn*16+c, to spatial-major att
    const int wl = win & 63, bb = win >> 6;
    const size_t obase = (size_t)bb * 3136 * DIMC;
    const int nsp0 = (wl >> 3) * 7 * HWIMG + (wl & 7) * 7;
    #pragma unroll
    for (int to = 0; to < 4; ++to) {
        #pragma unroll
        for (int e = 0; e < 4; ++e) {
            int i = to * 16 + g * 4 + e;
            if (i < 49) {
                int nsp = nsp0 + (i / 7) * HWIMG + (i % 7);
                unsigned short* ob = att + obase + (size_t)nsp * DIMC + head * HD;
                #pragma unroll
                for (int tn = 0; tn < 2; ++tn)
                    ob[tn * 16 + c] = f2bf(o[to][tn][e]);
            }
        }
    }
}

extern "C" void kernel_launch(void* const* d_in, const int* in_sizes, int n_in,
                              void* d_out, int out_size, void* d_ws, size_t ws_size,
                              hipStream_t stream) {
    const float* x          = (const float*)d_in[0];
    const float* w_qkv      = (const float*)d_in[1];
    const float* w_proj     = (const float*)d_in[2];
    const float* b_proj     = (const float*)d_in[3];
    const float* bias_table = (const float*)d_in[4];
    const int*   rel_index  = (const int*)d_in[5];

    // workspace layout (att aliases xt: xt consumed by GEMM1 before att is written)
    unsigned short* xt    = (unsigned short*)d_ws;                   // [NROWS][384]
    unsigned short* att   = xt;                                      // alias, spatial-major
    unsigned short* qkw   = xt + (size_t)NROWS * KDIM;               // [NROWS][768]
    unsigned short* vw    = qkw + (size_t)NROWS * 768;               // [NWIN][384][64]
    unsigned short* wq_pad = vw + (size_t)NWIN * 384 * 64;           // [1280][384]
    unsigned short* wpb   = wq_pad + (size_t)MPAD * KDIM;            // [384][384]
    float*          biasp = (float*)(wpb + DIMC * KDIM);             // [12][64][64]

    cvt_w<<<(MPAD * KDIM + 255) / 256, 256, 0, stream>>>(w_qkv, wq_pad, QKV_M * KDIM, MPAD * KDIM);
    cvt_w<<<(DIMC * KDIM + 255) / 256, 256, 0, stream>>>(w_proj, wpb, DIMC * KDIM, DIMC * KDIM);
    cvt_x<<<dim3(98, 12, BATCH), 256, 0, stream>>>(x, xt);
    fill_bias<<<192, 256, 0, stream>>>(bias_table, rel_index, biasp);
    zero_vpad<<<3072, 256, 0, stream>>>(vw);

    // GEMM1 (8-phase): 5 m-tiles x 392 n-tiles = 1960 blocks, 512 threads
    gemm_qkv8<<<1960, 512, 0, stream>>>(wq_pad, xt, qkw, vw);

    // attention: 24576 (win,head) waves, 4 per block
    win_attn<<<6144, 256, 0, stream>>>(qkw, vw, biasp, att);

    // GEMM2: 3 m-tiles x 784 n-tiles = 2352 blocks; spatial-major B, coalesced NCHW out
    gemm_proj<<<2352, 256, 0, stream>>>(wpb, att, b_proj, (float*)d_out);
}

// Round 13
// 323.573 us; speedup vs baseline: 1.6407x; 1.2687x over previous
//
#include <hip/hip_runtime.h>

#define NH 12
#define HD 32
#define DIMC 384
#define BATCH 32
#define HWIMG 56
#define NWIN 2048          // 32 batches * 64 windows
#define NROWS 100352       // NWIN * 49, dense window-gathered rows
#define QKV_M 1152
#define KDIM 384
#define QSCALE 0.17677669529663687f

typedef __attribute__((ext_vector_type(8))) short short8;
typedef __attribute__((ext_vector_type(4))) short short4v;
typedef __attribute__((ext_vector_type(4))) float f32x4;

typedef const __attribute__((address_space(1))) unsigned int* gas_ptr;
typedef __attribute__((address_space(3))) unsigned int* las_ptr;

__device__ __forceinline__ unsigned short f2bf(float f) {
    union { float f; unsigned u; } v; v.f = f;
    unsigned r = v.u + 0x7FFF + ((v.u >> 16) & 1);
    return (unsigned short)(r >> 16);
}

// ---------------- fp32 -> bf16 weight convert ----------------
__global__ __launch_bounds__(256) void cvt_w(const float* __restrict__ in,
                                             unsigned short* __restrict__ out, int n) {
    int i = blockIdx.x * 256 + threadIdx.x;
    if (i < n) out[i] = f2bf(in[i]);
}

// ---------------- x [B,384,56,56] fp32 -> xt [NROWS,384] bf16 (window-gathered) -------
__global__ __launch_bounds__(256) void cvt_x(const float* __restrict__ x,
                                             unsigned short* __restrict__ xt) {
    __shared__ float tile[32][33];
    const int b = blockIdx.z, c0 = blockIdx.y * 32, n0 = blockIdx.x * 32;
    const int tid = threadIdx.x;
    const int cl = tid >> 5, nl = tid & 31;
    #pragma unroll
    for (int p = 0; p < 4; ++p)
        tile[cl + p * 8][nl] = x[((size_t)b * DIMC + c0 + cl + p * 8) * 3136 + n0 + nl];
    __syncthreads();
    const int nl2 = tid >> 3, cq = (tid & 7) * 4;
    const int n = n0 + nl2;
    const int nh = n / HWIMG, nw = n % HWIMG;
    const int row = ((b * 64 + (nh / 7) * 8 + nw / 7) * 49 + (nh % 7) * 7 + nw % 7);
    short4v pk;
    #pragma unroll
    for (int u = 0; u < 4; ++u) pk[u] = (short)f2bf(tile[cq + u][nl2]);
    *(short4v*)(xt + (size_t)row * KDIM + c0 + cq) = pk;
}

// ---------------- bias expand: biasp[h][j:64][i:64] fp32, transposed & padded ----------
__global__ __launch_bounds__(256) void fill_bias(const float* __restrict__ bias_table,
                                                 const int* __restrict__ rel_index,
                                                 float* __restrict__ biasp) {
    int id = blockIdx.x * 256 + threadIdx.x;   // 12*4096
    int h = id >> 12, r = id & 4095;
    int j = r >> 6, i = r & 63;
    float v = 0.f;
    if (i < 49 && j < 49) v = bias_table[rel_index[i * 49 + j] * NH + h];
    biasp[id] = v;
}

// ============ GEMM1: QKV with LDS-bounced COALESCED epilogue ============
// R4-proven 2-phase K-loop (128x128 tile, MT=9, m-fastest XCD supertile).
// Epilogue: acc -> bf16 -> LDS tile [128 ng][128 m] (XOR-swizzled 16B chunks)
// -> 16-B wave-contiguous stores to qkw2[ng][1152].  No transposed scatter.
__global__ __launch_bounds__(256) void gemm_qkv(
    const unsigned short* __restrict__ A,     // wqb [1152][384]
    const unsigned short* __restrict__ Bm,    // xt [NROWS][384]
    unsigned short* __restrict__ qk)          // qkw2 [NROWS][1152]
{
    __shared__ char LBUF[32768];              // K-loop: A|B 16KB each; epilogue: C tile
    char* Al = LBUF;
    char* Bl = LBUF + 16384;
    const int tid = threadIdx.x;

    constexpr int MT = 9;
    const unsigned nwg = gridDim.x;
    const unsigned lin = blockIdx.x;
    const unsigned swz = (lin & 7) * (nwg >> 3) + (lin >> 3);  // XCD-contiguous
    const int m0 = (int)(swz % MT) * 128;
    const int ng0 = (int)(swz / MT) * 128;

    const int lane = tid & 63;
    const int wv = tid >> 6;
    const int wr = wv >> 1, wc = wv & 1;
    const int lrow = lane & 15, kgrp = lane >> 4;

    f32x4 acc[4][4] = {};

    const char* Abase = (const char*)(A + (size_t)m0 * KDIM);
    const char* Bbase = (const char*)(Bm + (size_t)ng0 * KDIM);

    for (int kt = 0; kt < KDIM / 64; ++kt) {
        const int kb = kt * 128;
        #pragma unroll
        for (int it = 0; it < 4; ++it) {
            int chunk = it * 256 + tid;
            int row = chunk >> 3, slot = chunk & 7;
            int scol = (slot ^ (row & 7)) * 16;
            __builtin_amdgcn_global_load_lds(
                (gas_ptr)(Abase + (size_t)row * (KDIM * 2) + kb + scol),
                (las_ptr)(Al + chunk * 16), 16, 0, 0);
        }
        #pragma unroll
        for (int it = 0; it < 4; ++it) {
            int chunk = it * 256 + tid;
            int row = chunk >> 3, slot = chunk & 7;
            int scol = (slot ^ (row & 7)) * 16;
            __builtin_amdgcn_global_load_lds(
                (gas_ptr)(Bbase + (size_t)row * (KDIM * 2) + kb + scol),
                (las_ptr)(Bl + chunk * 16), 16, 0, 0);
        }
        __syncthreads();
        #pragma unroll
        for (int kk = 0; kk < 2; ++kk) {
            short8 af[4], bfr[4];
            #pragma unroll
            for (int i = 0; i < 4; ++i) {
                int row = wr * 64 + i * 16 + lrow;
                int slot = (kk * 4 + kgrp) ^ (row & 7);
                af[i] = *(const short8*)(Al + row * 128 + slot * 16);
            }
            #pragma unroll
            for (int j = 0; j < 4; ++j) {
                int row = wc * 64 + j * 16 + lrow;
                int slot = (kk * 4 + kgrp) ^ (row & 7);
                bfr[j] = *(const short8*)(Bl + row * 128 + slot * 16);
            }
            __builtin_amdgcn_s_setprio(1);
            #pragma unroll
            for (int i = 0; i < 4; ++i)
                #pragma unroll
                for (int j = 0; j < 4; ++j)
                    acc[i][j] = __builtin_amdgcn_mfma_f32_16x16x32_bf16(af[i], bfr[j], acc[i][j], 0, 0, 0);
            __builtin_amdgcn_s_setprio(0);
        }
        __syncthreads();   // all LDS reads done -> safe to repurpose LBUF after loop
    }

    // ---- epilogue: C -> LDS [128 ng][256 B m-slice], XOR-swizzled 16B chunks ----
    const float sc = (m0 < 384) ? QSCALE : 1.0f;   // q/k boundary (384) is tile-aligned
    #pragma unroll
    for (int i = 0; i < 4; ++i) {
        int mpl = wr * 64 + i * 16 + kgrp * 4;     // local m (covers 4)
        #pragma unroll
        for (int j = 0; j < 4; ++j) {
            int ngl = wc * 64 + j * 16 + lrow;     // local ng
            short4v pk;
            pk.x = (short)f2bf(acc[i][j].x * sc);
            pk.y = (short)f2bf(acc[i][j].y * sc);
            pk.z = (short)f2bf(acc[i][j].z * sc);
            pk.w = (short)f2bf(acc[i][j].w * sc);
            *(short4v*)(LBUF + ngl * 256 + ((mpl * 2) ^ ((ngl & 7) << 4))) = pk;
        }
    }
    __syncthreads();
    // ---- coalesced store: 2048 16-B chunks, 8 per thread ----
    #pragma unroll
    for (int p = 0; p < 8; ++p) {
        int ch = p * 256 + tid;
        int ngl = ch >> 4, q = ch & 15;
        short8 v = *(const short8*)(LBUF + ngl * 256 + ((q * 16) ^ ((ngl & 7) << 4)));
        *(short8*)(qk + (size_t)(ng0 + ngl) * QKV_M + m0 + q * 8) = v;
    }
}

// ---------------- proj GEMM (R4-proven): C = w_proj @ att^T + bias, fp32 NCHW -------
__global__ __launch_bounds__(256) void gemm_proj(
    const unsigned short* __restrict__ A,     // [384][384] bf16
    const unsigned short* __restrict__ Bm,    // att [NROWS][384] spatial-major
    const float* __restrict__ bias,
    float* __restrict__ C)
{
    __shared__ char Al[128 * 128];
    __shared__ char Bl[128 * 128];
    const int tid = threadIdx.x;

    constexpr int MT = 3;
    const unsigned nwg = gridDim.x;
    const unsigned lin = blockIdx.x;
    const unsigned swz = (lin & 7) * (nwg >> 3) + (lin >> 3);
    const int m0 = (int)(swz % MT) * 128;
    const int ng0 = (int)(swz / MT) * 128;

    const int lane = tid & 63;
    const int wv = tid >> 6;
    const int wr = wv >> 1, wc = wv & 1;
    const int lrow = lane & 15, kgrp = lane >> 4;

    f32x4 acc[4][4] = {};

    const char* Abase = (const char*)(A + (size_t)m0 * KDIM);
    const char* Bbase = (const char*)(Bm + (size_t)ng0 * KDIM);

    for (int kt = 0; kt < KDIM / 64; ++kt) {
        const int kb = kt * 128;
        #pragma unroll
        for (int it = 0; it < 4; ++it) {
            int chunk = it * 256 + tid;
            int row = chunk >> 3, slot = chunk & 7;
            int scol = (slot ^ (row & 7)) * 16;
            __builtin_amdgcn_global_load_lds(
                (gas_ptr)(Abase + (size_t)row * (KDIM * 2) + kb + scol),
                (las_ptr)(Al + chunk * 16), 16, 0, 0);
        }
        #pragma unroll
        for (int it = 0; it < 4; ++it) {
            int chunk = it * 256 + tid;
            int row = chunk >> 3, slot = chunk & 7;
            int scol = (slot ^ (row & 7)) * 16;
            __builtin_amdgcn_global_load_lds(
                (gas_ptr)(Bbase + (size_t)row * (KDIM * 2) + kb + scol),
                (las_ptr)(Bl + chunk * 16), 16, 0, 0);
        }
        __syncthreads();
        #pragma unroll
        for (int kk = 0; kk < 2; ++kk) {
            short8 af[4], bfr[4];
            #pragma unroll
            for (int i = 0; i < 4; ++i) {
                int row = wr * 64 + i * 16 + lrow;
                int slot = (kk * 4 + kgrp) ^ (row & 7);
                af[i] = *(const short8*)(Al + row * 128 + slot * 16);
            }
            #pragma unroll
            for (int j = 0; j < 4; ++j) {
                int row = wc * 64 + j * 16 + lrow;
                int slot = (kk * 4 + kgrp) ^ (row & 7);
                bfr[j] = *(const short8*)(Bl + row * 128 + slot * 16);
            }
            __builtin_amdgcn_s_setprio(1);
            #pragma unroll
            for (int i = 0; i < 4; ++i)
                #pragma unroll
                for (int j = 0; j < 4; ++j)
                    acc[i][j] = __builtin_amdgcn_mfma_f32_16x16x32_bf16(af[i], bfr[j], acc[i][j], 0, 0, 0);
            __builtin_amdgcn_s_setprio(0);
        }
        __syncthreads();
    }

    #pragma unroll
    for (int i = 0; i < 4; ++i) {
        int m = m0 + wr * 64 + i * 16 + kgrp * 4;
        float b0 = bias[m + 0], b1 = bias[m + 1], b2 = bias[m + 2], b3 = bias[m + 3];
        #pragma unroll
        for (int j = 0; j < 4; ++j) {
            int ng = ng0 + wc * 64 + j * 16 + lrow;
            unsigned bb = (unsigned)ng / 3136u;
            unsigned nsp = (unsigned)ng - bb * 3136u;
            C[((size_t)bb * DIMC + m + 0) * 3136 + nsp] = acc[i][j].x + b0;
            C[((size_t)bb * DIMC + m + 1) * 3136 + nsp] = acc[i][j].y + b1;
            C[((size_t)bb * DIMC + m + 2) * 3136 + nsp] = acc[i][j].z + b2;
            C[((size_t)bb * DIMC + m + 3) * 3136 + nsp] = acc[i][j].w + b3;
        }
    }
}

// ---------------- MFMA windowed attention: one wave per (window, head) -------
// q/k read from qkw2 [NROWS][1152]; V staged per-wave into LDS [32 d][72] (transposed).
// Output att is SPATIAL-major: row = b*3136 + nsp.
__global__ __launch_bounds__(256) void win_attn(
    const unsigned short* __restrict__ qkw,   // [NROWS][1152], q pre-scaled
    const float* __restrict__ biasp,          // [12][64][64]  (j-major, transposed)
    unsigned short* __restrict__ att)         // [B*3136][384] spatial-major
{
    __shared__ short Vl[4][32 * 72];          // per-wave V^T region, stride 72
    const int tid = threadIdx.x;
    const int lane = tid & 63;
    const int wv = tid >> 6;
    const int g = lane >> 4, c = lane & 15;
    const int bid = blockIdx.x;
    const int swz = (bid & 7) * 768 + (bid >> 3);       // 6144 blocks
    const int W = swz * 4 + wv;
    const int win = W / 12;
    const int head = W - win * 12;

    short* Vw = Vl[wv];

    // zero-fill pad columns j=49..63 (read by vf; must be finite)
    #pragma unroll
    for (int u = 0; u < 8; ++u) {
        int id = u * 64 + lane;
        if (id < 480) {
            int d = id / 15, jj = 49 + id % 15;
            Vw[d * 72 + jj] = 0;
        }
    }

    const unsigned short* qbase = qkw + (size_t)win * 49 * QKV_M + head * HD;

    short8 kf[4], qf[4];
    #pragma unroll
    for (int a = 0; a < 4; ++a) {
        int r = a * 16 + c; if (r > 48) r = 48;
        qf[a] = *(const short8*)(qbase + (size_t)r * QKV_M + g * 8);
        kf[a] = *(const short8*)(qbase + (size_t)r * QKV_M + DIMC + g * 8);
    }

    // stage V^T: rows r<49, 8-ch chunks; transposed scalar writes into Vw[d][j=r]
    const unsigned short* vsrc = qbase + 2 * DIMC;
    #pragma unroll
    for (int p = 0; p < 4; ++p) {
        int r = p * 16 + (lane >> 2);
        int chk = (lane & 3) * 8;
        if (r < 49) {
            short8 v8 = *(const short8*)(vsrc + (size_t)r * QKV_M + chk);
            #pragma unroll
            for (int u = 0; u < 8; ++u)
                Vw[(chk + u) * 72 + r] = v8[u];
        }
    }

    // S^T fragments: rows j = a*16+g*4+e, cols i = bi*16+c
    f32x4 s[4][4] = {};
    #pragma unroll
    for (int a = 0; a < 4; ++a)
        #pragma unroll
        for (int bi = 0; bi < 4; ++bi)
            s[a][bi] = __builtin_amdgcn_mfma_f32_16x16x32_bf16(kf[a], qf[bi], s[a][bi], 0, 0, 0);

    const float* bp = biasp + head * 4096;
    #pragma unroll
    for (int bi = 0; bi < 4; ++bi) {
        float mx = -1e30f;
        #pragma unroll
        for (int a = 0; a < 4; ++a) {
            #pragma unroll
            for (int e = 0; e < 4; ++e) {
                int j = a * 16 + g * 4 + e;
                float sv = s[a][bi][e] + bp[j * 64 + bi * 16 + c];
                sv = (j < 49) ? sv : -1e30f;
                s[a][bi][e] = sv;
                mx = fmaxf(mx, sv);
            }
        }
        mx = fmaxf(mx, __shfl_xor(mx, 16));
        mx = fmaxf(mx, __shfl_xor(mx, 32));
        float sum = 0.f;
        #pragma unroll
        for (int a = 0; a < 4; ++a) {
            #pragma unroll
            for (int e = 0; e < 4; ++e) {
                int j = a * 16 + g * 4 + e;
                float pv = (j < 49) ? __expf(s[a][bi][e] - mx) : 0.f;
                s[a][bi][e] = pv;
                sum += pv;
            }
        }
        sum += __shfl_xor(sum, 16);
        sum += __shfl_xor(sum, 32);
        float inv = 1.0f / sum;
        #pragma unroll
        for (int a = 0; a < 4; ++a)
            #pragma unroll
            for (int e = 0; e < 4; ++e)
                s[a][bi][e] *= inv;
    }

    unsigned pk[4][4][2];
    #pragma unroll
    for (int a = 0; a < 4; ++a)
        #pragma unroll
        for (int bi = 0; bi < 4; ++bi)
            #pragma unroll
            for (int h = 0; h < 2; ++h)
                pk[a][bi][h] = (unsigned)f2bf(s[a][bi][2 * h]) |
                               ((unsigned)f2bf(s[a][bi][2 * h + 1]) << 16);

    // V fragments from per-wave LDS (in-wave ds ordering; compiler inserts lgkmcnt)
    short8 vf[2][2];
    #pragma unroll
    for (int tn = 0; tn < 2; ++tn)
        #pragma unroll
        for (int ks = 0; ks < 2; ++ks)
            vf[tn][ks] = *(const short8*)(&Vw[(tn * 16 + c) * 72 + ks * 32 + g * 8]);

    f32x4 o[4][2] = {};
    const int gsel = g >> 1;
    const int sgb = 2 * (g & 1);
    #pragma unroll
    for (int ks = 0; ks < 2; ++ks) {
        #pragma unroll
        for (int to = 0; to < 4; ++to) {
            union { int w[4]; short8 v; } u;
            #pragma unroll
            for (int w = 0; w < 4; ++w) {
                int srcl = ((sgb + (w >> 1)) * 16 + c) << 2;
                int rA = __builtin_amdgcn_ds_bpermute(srcl, (int)pk[ks * 2 + 0][to][w & 1]);
                int rB = __builtin_amdgcn_ds_bpermute(srcl, (int)pk[ks * 2 + 1][to][w & 1]);
                u.w[w] = gsel ? rB : rA;
            }
            #pragma unroll
            for (int tn = 0; tn < 2; ++tn)
                o[to][tn] = __builtin_amdgcn_mfma_f32_16x16x32_bf16(u.v, vf[tn][ks], o[to][tn], 0, 0, 0);
        }
    }

    // store O rows i = to*16+g*4+e (i<49), cols d = tn*16+c, to spatial-major att
    const int wl = win & 63, bb = win >> 6;
    const size_t obase = (size_t)bb * 3136 * DIMC;
    const int nsp0 = (wl >> 3) * 7 * HWIMG + (wl & 7) * 7;
    #pragma unroll
    for (int to = 0; to < 4; ++to) {
        #pragma unroll
        for (int e = 0; e < 4; ++e) {
            int i = to * 16 + g * 4 + e;
            if (i < 49) {
                int nsp = nsp0 + (i / 7) * HWIMG + (i % 7);
                unsigned short* ob = att + obase + (size_t)nsp * DIMC + head * HD;
                #pragma unroll
                for (int tn = 0; tn < 2; ++tn)
                    ob[tn * 16 + c] = f2bf(o[to][tn][e]);
            }
        }
    }
}

extern "C" void kernel_launch(void* const* d_in, const int* in_sizes, int n_in,
                              void* d_out, int out_size, void* d_ws, size_t ws_size,
                              hipStream_t stream) {
    const float* x          = (const float*)d_in[0];
    const float* w_qkv      = (const float*)d_in[1];
    const float* w_proj     = (const float*)d_in[2];
    const float* b_proj     = (const float*)d_in[3];
    const float* bias_table = (const float*)d_in[4];
    const int*   rel_index  = (const int*)d_in[5];

    // workspace (att aliases xt: xt fully consumed by GEMM1 before att is written)
    unsigned short* xt    = (unsigned short*)d_ws;                   // [NROWS][384]
    unsigned short* att   = xt;                                      // alias, spatial-major
    unsigned short* qkw2  = xt + (size_t)NROWS * KDIM;               // [NROWS][1152]
    unsigned short* wqb   = qkw2 + (size_t)NROWS * QKV_M;            // [1152][384]
    unsigned short* wpb   = wqb + QKV_M * KDIM;                      // [384][384]
    float*          biasp = (float*)(wpb + DIMC * KDIM);             // [12][64][64]

    cvt_w<<<(QKV_M * KDIM + 255) / 256, 256, 0, stream>>>(w_qkv, wqb, QKV_M * KDIM);
    cvt_w<<<(DIMC * KDIM + 255) / 256, 256, 0, stream>>>(w_proj, wpb, DIMC * KDIM);
    cvt_x<<<dim3(98, 12, BATCH), 256, 0, stream>>>(x, xt);
    fill_bias<<<192, 256, 0, stream>>>(bias_table, rel_index, biasp);

    // GEMM1: 9 m-tiles x 784 n-tiles = 7056 blocks; coalesced epilogue
    gemm_qkv<<<7056, 256, 0, stream>>>(wqb, xt, qkw2);

    // attention: 24576 (win,head) waves, 4 per block
    win_attn<<<6144, 256, 0, stream>>>(qkw2, biasp, att);

    // GEMM2: 3 m-tiles x 784 n-tiles = 2352 blocks; spatial-major B, coalesced NCHW out
    gemm_proj<<<2352, 256, 0, stream>>>(wpb, att, b_proj, (float*)d_out);
}